// Round 9
// baseline (669.762 us; speedup 1.0000x reference)
//
#include <hip/hip_runtime.h>
#include <hip/hip_fp16.h>

#define THREADS 256

typedef int int4v __attribute__((ext_vector_type(4)));

// ws layout:
//   ws[0] (double)  = sum over edges of (1-p_u)(1-p_v) for u!=v
//   ws[1] (double)  = sum over nodes of probs
//   byte offset 256 = fp16 table q[i] = 1 - probs[i], N_NODES+1 entries
//                     (entry N_NODES is a 0.0 sentinel for self-loop edges)

__device__ __forceinline__ float h2f_bits(unsigned v) {
    __half_raw hr;
    hr.x = (unsigned short)v;
    return __half2float((__half)hr);
}

__device__ __forceinline__ void block_reduce_atomic(float local, double* dst,
                                                    double* sdata) {
    double d = (double)local;
    #pragma unroll
    for (int off = 32; off > 0; off >>= 1)
        d += __shfl_down(d, off, 64);
    int lane = threadIdx.x & 63;
    int wid  = threadIdx.x >> 6;
    if (lane == 0) sdata[wid] = d;
    __syncthreads();
    if (threadIdx.x == 0) {
        double s = 0.0;
        #pragma unroll
        for (int i = 0; i < (THREADS / 64); ++i) s += sdata[i];
        atomicAdd(dst, s);
    }
}

// Build q = 1 - p as fp16 table (+ zero sentinel); fused: reduce sum(probs).
__global__ void __launch_bounds__(THREADS) build_table_kernel(
        const float* __restrict__ probs,
        unsigned short* __restrict__ qt,
        double* __restrict__ ws,
        long long n_nodes) {
    __shared__ double sdata[THREADS / 64];
    long long n4 = n_nodes >> 2;
    const float4* p4 = (const float4*)probs;
    ushort4* q4 = (ushort4*)qt;
    long long tid = (long long)blockIdx.x * blockDim.x + threadIdx.x;
    long long stride = (long long)gridDim.x * blockDim.x;

    if (tid == 0) qt[n_nodes] = (unsigned short)0;  // sentinel: fp16 +0.0

    float local = 0.0f;
    for (long long i = tid; i < n4; i += stride) {
        float4 v = p4[i];
        local += (v.x + v.y) + (v.z + v.w);
        ushort4 q;
        q.x = __half_as_ushort(__float2half(1.0f - v.x));
        q.y = __half_as_ushort(__float2half(1.0f - v.y));
        q.z = __half_as_ushort(__float2half(1.0f - v.z));
        q.w = __half_as_ushort(__float2half(1.0f - v.w));
        q4[i] = q;
    }
    for (long long i = (n4 << 2) + tid; i < n_nodes; i += stride) {
        float p = probs[i];
        local += p;
        qt[i] = __half_as_ushort(__float2half(1.0f - p));
    }

    block_reduce_atomic(local, ws + 1, sdata);
}

// FINAL PROBE: 4 edges (8 gathers) per thread, 8M threads — maximum wave
// churn (fast wave retirement keeps the CU miss queue fed by fresh waves).
// Gathers use `nt` (L1 no-allocate): if miss-entry recycling is L1-side this
// frees entries earlier; neutral if the floor is L2-side.
__global__ void edge_sum_kernel(
        const unsigned short* __restrict__ qt,
        const int* __restrict__ row,
        const int* __restrict__ col,
        double* __restrict__ ws,
        long long n_edges,
        int sentinel) {
    __shared__ double sdata[THREADS / 64];
    long long n4 = n_edges >> 2;   // int4 groups; T = n4 threads (4 edges each)
    long long t  = (long long)blockIdx.x * blockDim.x + threadIdx.x;

    const int4v* row4 = (const int4v*)row;
    const int4v* col4 = (const int4v*)col;

    float local = 0.0f;
    if (t < n4) {
        int4v u = __builtin_nontemporal_load(&row4[t]);
        int4v v = __builtin_nontemporal_load(&col4[t]);

        int v0 = (u.x == v.x) ? sentinel : v.x;
        int v1 = (u.y == v.y) ? sentinel : v.y;
        int v2 = (u.z == v.z) ? sentinel : v.z;
        int v3 = (u.w == v.w) ? sentinel : v.w;

        unsigned long long base = (unsigned long long)qt;
        unsigned a0, a1, a2, a3, b0, b1, b2, b3;
        {
            unsigned long long x0 = base + 2ull * (unsigned)u.x;
            unsigned long long x1 = base + 2ull * (unsigned)u.y;
            unsigned long long x2 = base + 2ull * (unsigned)u.z;
            unsigned long long x3 = base + 2ull * (unsigned)u.w;
            unsigned long long y0 = base + 2ull * (unsigned)v0;
            unsigned long long y1 = base + 2ull * (unsigned)v1;
            unsigned long long y2 = base + 2ull * (unsigned)v2;
            unsigned long long y3 = base + 2ull * (unsigned)v3;
            asm volatile("global_load_ushort %0, %1, off nt" : "=v"(a0) : "v"(x0));
            asm volatile("global_load_ushort %0, %1, off nt" : "=v"(a1) : "v"(x1));
            asm volatile("global_load_ushort %0, %1, off nt" : "=v"(a2) : "v"(x2));
            asm volatile("global_load_ushort %0, %1, off nt" : "=v"(a3) : "v"(x3));
            asm volatile("global_load_ushort %0, %1, off nt" : "=v"(b0) : "v"(y0));
            asm volatile("global_load_ushort %0, %1, off nt" : "=v"(b1) : "v"(y1));
            asm volatile("global_load_ushort %0, %1, off nt" : "=v"(b2) : "v"(y2));
            asm volatile("global_load_ushort %0, %1, off nt" : "=v"(b3) : "v"(y3));
        }
        asm volatile("s_waitcnt vmcnt(0)" ::: "memory");
        __builtin_amdgcn_sched_barrier(0);

        local += h2f_bits(a0) * h2f_bits(b0);
        local += h2f_bits(a1) * h2f_bits(b1);
        local += h2f_bits(a2) * h2f_bits(b2);
        local += h2f_bits(a3) * h2f_bits(b3);
    }

    // tail: edges past 4*n4 (empty when n_edges % 4 == 0)
    long long covered = n4 << 2;
    long long total_threads = (long long)gridDim.x * blockDim.x;
    for (long long e = covered + t; e < n_edges; e += total_threads) {
        int uu = row[e], vv = col[e];
        int vr = (uu == vv) ? sentinel : vv;
        local += h2f_bits(qt[uu]) * h2f_bits(qt[vr]);
    }

    block_reduce_atomic(local, ws, sdata);
}

__global__ void finalize_kernel(const double* __restrict__ ws,
                                const int* __restrict__ batch,
                                long long n_nodes,
                                const float* __restrict__ pc,
                                float* __restrict__ out) {
    double edge_s = ws[0];
    double prob_s = ws[1];
    double G = (double)(batch[n_nodes - 1] + 1);  // batch is sorted
    double ed = edge_s / G;
    double ew = prob_s / G;
    double loss = (double)pc[0] * ed + ew;
    out[0] = (float)loss;
    out[1] = (float)ew;
    out[2] = (float)ed;
}

extern "C" void kernel_launch(void* const* d_in, const int* in_sizes, int n_in,
                              void* d_out, int out_size, void* d_ws, size_t ws_size,
                              hipStream_t stream) {
    const float* probs = (const float*)d_in[0];
    const int* edge_index = (const int*)d_in[1];   // harness passes integers as int32
    const int* batch = (const int*)d_in[2];
    const float* pc = (const float*)d_in[3];

    long long n_nodes = (long long)in_sizes[0];
    long long n_edges = (long long)in_sizes[1] / 2;
    const int* row = edge_index;
    const int* col = edge_index + n_edges;

    double* ws = (double*)d_ws;
    hipMemsetAsync(ws, 0, 2 * sizeof(double), stream);

    unsigned short* qt = (unsigned short*)((char*)d_ws + 256);
    build_table_kernel<<<512, THREADS, 0, stream>>>(probs, qt, ws, n_nodes);

    long long T = n_edges >> 2;                  // 4 edges per thread
    long long blocks = (T + THREADS - 1) / THREADS;
    if (blocks < 1) blocks = 1;
    edge_sum_kernel<<<(int)blocks, THREADS, 0, stream>>>(qt, row, col, ws,
                                                         n_edges, (int)n_nodes);

    finalize_kernel<<<1, 1, 0, stream>>>(ws, batch, n_nodes, pc, (float*)d_out);
}

// Round 10
// 416.845 us; speedup vs baseline: 1.6067x; 1.6067x over previous
//
#include <hip/hip_runtime.h>
#include <hip/hip_fp16.h>

#define THREADS 256

typedef int int4v __attribute__((ext_vector_type(4)));

// ws layout:
//   ws[0] (double)  = sum over edges of (1-p_u)(1-p_v) for u!=v
//   ws[1] (double)  = sum over nodes of probs
//   byte offset 256 = fp16 table q[i] = 1 - probs[i], N_NODES+1 entries
//                     (entry N_NODES is a 0.0 sentinel for self-loop edges)

__device__ __forceinline__ float h2f_bits(unsigned v) {
    __half_raw hr;
    hr.x = (unsigned short)v;
    return __half2float((__half)hr);
}

__device__ __forceinline__ void block_reduce_atomic(float local, double* dst,
                                                    double* sdata) {
    double d = (double)local;
    #pragma unroll
    for (int off = 32; off > 0; off >>= 1)
        d += __shfl_down(d, off, 64);
    int lane = threadIdx.x & 63;
    int wid  = threadIdx.x >> 6;
    if (lane == 0) sdata[wid] = d;
    __syncthreads();
    if (threadIdx.x == 0) {
        double s = 0.0;
        #pragma unroll
        for (int i = 0; i < (THREADS / 64); ++i) s += sdata[i];
        atomicAdd(dst, s);
    }
}

// Build q = 1 - p as fp16 table (+ zero sentinel); fused: reduce sum(probs).
__global__ void __launch_bounds__(THREADS) build_table_kernel(
        const float* __restrict__ probs,
        unsigned short* __restrict__ qt,
        double* __restrict__ ws,
        long long n_nodes) {
    __shared__ double sdata[THREADS / 64];
    long long n4 = n_nodes >> 2;
    const float4* p4 = (const float4*)probs;
    ushort4* q4 = (ushort4*)qt;
    long long tid = (long long)blockIdx.x * blockDim.x + threadIdx.x;
    long long stride = (long long)gridDim.x * blockDim.x;

    if (tid == 0) qt[n_nodes] = (unsigned short)0;  // sentinel: fp16 +0.0

    float local = 0.0f;
    for (long long i = tid; i < n4; i += stride) {
        float4 v = p4[i];
        local += (v.x + v.y) + (v.z + v.w);
        ushort4 q;
        q.x = __half_as_ushort(__float2half(1.0f - v.x));
        q.y = __half_as_ushort(__float2half(1.0f - v.y));
        q.z = __half_as_ushort(__float2half(1.0f - v.z));
        q.w = __half_as_ushort(__float2half(1.0f - v.w));
        q4[i] = q;
    }
    for (long long i = (n4 << 2) + tid; i < n_nodes; i += stride) {
        float p = probs[i];
        local += p;
        qt[i] = __half_as_ushort(__float2half(1.0f - p));
    }

    block_reduce_atomic(local, ws + 1, sdata);
}

// Clean wave-churn probe: 4 edges (8 gathers) per thread, 8M threads, plain
// CACHED loads (round 9's `nt` killed L2 residency of the table -> 1.7 GB
// HBM fetch; never use nt on the gathers). Minimal VGPR -> max occupancy,
// fast wave retirement keeps the per-CU miss queue fed by fresh waves.
__global__ void edge_sum_kernel(
        const unsigned short* __restrict__ qt,
        const int* __restrict__ row,
        const int* __restrict__ col,
        double* __restrict__ ws,
        long long n_edges,
        int sentinel) {
    __shared__ double sdata[THREADS / 64];
    long long n4 = n_edges >> 2;   // int4 groups; T = n4 threads (4 edges each)
    long long t  = (long long)blockIdx.x * blockDim.x + threadIdx.x;

    const int4v* row4 = (const int4v*)row;
    const int4v* col4 = (const int4v*)col;

    float local = 0.0f;
    if (t < n4) {
        int4v u = __builtin_nontemporal_load(&row4[t]);   // nt OK: streamed once
        int4v v = __builtin_nontemporal_load(&col4[t]);

        int v0 = (u.x == v.x) ? sentinel : v.x;
        int v1 = (u.y == v.y) ? sentinel : v.y;
        int v2 = (u.z == v.z) ? sentinel : v.z;
        int v3 = (u.w == v.w) ? sentinel : v.w;

        // 8 independent cached gathers (compiler-scheduled)
        unsigned a0 = qt[u.x], b0 = qt[v0];
        unsigned a1 = qt[u.y], b1 = qt[v1];
        unsigned a2 = qt[u.z], b2 = qt[v2];
        unsigned a3 = qt[u.w], b3 = qt[v3];

        local += h2f_bits(a0) * h2f_bits(b0);
        local += h2f_bits(a1) * h2f_bits(b1);
        local += h2f_bits(a2) * h2f_bits(b2);
        local += h2f_bits(a3) * h2f_bits(b3);
    }

    // tail: edges past 4*n4 (empty when n_edges % 4 == 0)
    long long covered = n4 << 2;
    long long total_threads = (long long)gridDim.x * blockDim.x;
    for (long long e = covered + t; e < n_edges; e += total_threads) {
        int uu = row[e], vv = col[e];
        int vr = (uu == vv) ? sentinel : vv;
        local += h2f_bits(qt[uu]) * h2f_bits(qt[vr]);
    }

    block_reduce_atomic(local, ws, sdata);
}

__global__ void finalize_kernel(const double* __restrict__ ws,
                                const int* __restrict__ batch,
                                long long n_nodes,
                                const float* __restrict__ pc,
                                float* __restrict__ out) {
    double edge_s = ws[0];
    double prob_s = ws[1];
    double G = (double)(batch[n_nodes - 1] + 1);  // batch is sorted
    double ed = edge_s / G;
    double ew = prob_s / G;
    double loss = (double)pc[0] * ed + ew;
    out[0] = (float)loss;
    out[1] = (float)ew;
    out[2] = (float)ed;
}

extern "C" void kernel_launch(void* const* d_in, const int* in_sizes, int n_in,
                              void* d_out, int out_size, void* d_ws, size_t ws_size,
                              hipStream_t stream) {
    const float* probs = (const float*)d_in[0];
    const int* edge_index = (const int*)d_in[1];   // harness passes integers as int32
    const int* batch = (const int*)d_in[2];
    const float* pc = (const float*)d_in[3];

    long long n_nodes = (long long)in_sizes[0];
    long long n_edges = (long long)in_sizes[1] / 2;
    const int* row = edge_index;
    const int* col = edge_index + n_edges;

    double* ws = (double*)d_ws;
    hipMemsetAsync(ws, 0, 2 * sizeof(double), stream);

    unsigned short* qt = (unsigned short*)((char*)d_ws + 256);
    build_table_kernel<<<512, THREADS, 0, stream>>>(probs, qt, ws, n_nodes);

    long long T = n_edges >> 2;                  // 4 edges per thread
    long long blocks = (T + THREADS - 1) / THREADS;
    if (blocks < 1) blocks = 1;
    edge_sum_kernel<<<(int)blocks, THREADS, 0, stream>>>(qt, row, col, ws,
                                                         n_edges, (int)n_nodes);

    finalize_kernel<<<1, 1, 0, stream>>>(ws, batch, n_nodes, pc, (float*)d_out);
}

// Round 11
// 309.602 us; speedup vs baseline: 2.1633x; 1.3464x over previous
//
#include <hip/hip_runtime.h>
#include <hip/hip_fp16.h>

#define THREADS 256

typedef int int4v __attribute__((ext_vector_type(4)));

// ws layout:
//   ws[0] (double)  = sum over edges of (1-p_u)(1-p_v) for u!=v
//   ws[1] (double)  = sum over nodes of probs
//   byte offset 256 = fp16 table q[i] = 1 - probs[i], N_NODES+1 entries
//                     (entry N_NODES is a 0.0 sentinel for self-loop edges)
//
// Tuning record (rounds 2-10):
//   fp32 direct gather: 2.16 GB fetch, 569 us (table > 4 MiB/XCD L2)
//   fp16 table (4 MB, L2-resident): 328 MB fetch, 365 us
//   8 edges/thread exact-cover: 291 us   <- best; restored here
//   16/32 edges/thread, sched fences, volatile-asm batches: 298-305 us (flat)
//   4 edges/thread (max churn): 400 us (reduce overhead amortized worse)
//   `nt` on gathers: 670 us, 1.7 GB fetch (nt bypasses L2 on gfx950 - never)
// Invariant: cached random-gather rate pinned at 0.35-0.36 lines/cyc/CU
// across every structural variation => L2 random-request floor (~70% of the
// perfect 1 req/cyc/channel bound). This config is the roofline.

__device__ __forceinline__ float h2f_bits(unsigned v) {
    __half_raw hr;
    hr.x = (unsigned short)v;
    return __half2float((__half)hr);
}

__device__ __forceinline__ void block_reduce_atomic(float local, double* dst,
                                                    double* sdata) {
    double d = (double)local;
    #pragma unroll
    for (int off = 32; off > 0; off >>= 1)
        d += __shfl_down(d, off, 64);
    int lane = threadIdx.x & 63;
    int wid  = threadIdx.x >> 6;
    if (lane == 0) sdata[wid] = d;
    __syncthreads();
    if (threadIdx.x == 0) {
        double s = 0.0;
        #pragma unroll
        for (int i = 0; i < (THREADS / 64); ++i) s += sdata[i];
        atomicAdd(dst, s);
    }
}

// Build q = 1 - p as fp16 table (+ zero sentinel); fused: reduce sum(probs).
__global__ void __launch_bounds__(THREADS) build_table_kernel(
        const float* __restrict__ probs,
        unsigned short* __restrict__ qt,
        double* __restrict__ ws,
        long long n_nodes) {
    __shared__ double sdata[THREADS / 64];
    long long n4 = n_nodes >> 2;
    const float4* p4 = (const float4*)probs;
    ushort4* q4 = (ushort4*)qt;
    long long tid = (long long)blockIdx.x * blockDim.x + threadIdx.x;
    long long stride = (long long)gridDim.x * blockDim.x;

    if (tid == 0) qt[n_nodes] = (unsigned short)0;  // sentinel: fp16 +0.0

    float local = 0.0f;
    for (long long i = tid; i < n4; i += stride) {
        float4 v = p4[i];
        local += (v.x + v.y) + (v.z + v.w);
        ushort4 q;
        q.x = __half_as_ushort(__float2half(1.0f - v.x));
        q.y = __half_as_ushort(__float2half(1.0f - v.y));
        q.z = __half_as_ushort(__float2half(1.0f - v.z));
        q.w = __half_as_ushort(__float2half(1.0f - v.w));
        q4[i] = q;
    }
    for (long long i = (n4 << 2) + tid; i < n_nodes; i += stride) {
        float p = probs[i];
        local += p;
        qt[i] = __half_as_ushort(__float2half(1.0f - p));
    }

    block_reduce_atomic(local, ws + 1, sdata);
}

// Best config: 8 edges (16 gathers) per thread, exact cover, cached gathers
// with zero-extended uint dests (global_load_ushort, no d16 RMW pairing),
// self-loops redirected to the zero sentinel at address generation.
__global__ void edge_sum_kernel(
        const unsigned short* __restrict__ qt,
        const int* __restrict__ row,
        const int* __restrict__ col,
        double* __restrict__ ws,
        long long n_edges,
        int sentinel) {
    __shared__ double sdata[THREADS / 64];
    long long n4 = n_edges >> 2;   // int4 groups
    long long T  = n4 >> 1;        // 2 groups (8 edges) per thread
    long long t  = (long long)blockIdx.x * blockDim.x + threadIdx.x;

    const int4v* row4 = (const int4v*)row;
    const int4v* col4 = (const int4v*)col;

    float local = 0.0f;
    if (t < T) {
        int4v u0 = __builtin_nontemporal_load(&row4[t]);       // nt OK: streamed once
        int4v v0 = __builtin_nontemporal_load(&col4[t]);
        int4v u1 = __builtin_nontemporal_load(&row4[t + T]);
        int4v v1 = __builtin_nontemporal_load(&col4[t + T]);

        int w0 = (u0.x == v0.x) ? sentinel : v0.x;
        int w1 = (u0.y == v0.y) ? sentinel : v0.y;
        int w2 = (u0.z == v0.z) ? sentinel : v0.z;
        int w3 = (u0.w == v0.w) ? sentinel : v0.w;
        int w4 = (u1.x == v1.x) ? sentinel : v1.x;
        int w5 = (u1.y == v1.y) ? sentinel : v1.y;
        int w6 = (u1.z == v1.z) ? sentinel : v1.z;
        int w7 = (u1.w == v1.w) ? sentinel : v1.w;

        // 16 independent cached gathers, uint dests (compiler-scheduled)
        unsigned a0 = qt[u0.x], b0 = qt[w0];
        unsigned a1 = qt[u0.y], b1 = qt[w1];
        unsigned a2 = qt[u0.z], b2 = qt[w2];
        unsigned a3 = qt[u0.w], b3 = qt[w3];
        unsigned a4 = qt[u1.x], b4 = qt[w4];
        unsigned a5 = qt[u1.y], b5 = qt[w5];
        unsigned a6 = qt[u1.z], b6 = qt[w6];
        unsigned a7 = qt[u1.w], b7 = qt[w7];

        local += h2f_bits(a0) * h2f_bits(b0);
        local += h2f_bits(a1) * h2f_bits(b1);
        local += h2f_bits(a2) * h2f_bits(b2);
        local += h2f_bits(a3) * h2f_bits(b3);
        local += h2f_bits(a4) * h2f_bits(b4);
        local += h2f_bits(a5) * h2f_bits(b5);
        local += h2f_bits(a6) * h2f_bits(b6);
        local += h2f_bits(a7) * h2f_bits(b7);
    }

    // tail: edges past 8*T (empty when n_edges % 8 == 0)
    long long covered = T << 3;
    long long total_threads = (long long)gridDim.x * blockDim.x;
    for (long long e = covered + t; e < n_edges; e += total_threads) {
        int uu = row[e], vv = col[e];
        int vr = (uu == vv) ? sentinel : vv;
        local += h2f_bits(qt[uu]) * h2f_bits(qt[vr]);
    }

    block_reduce_atomic(local, ws, sdata);
}

__global__ void finalize_kernel(const double* __restrict__ ws,
                                const int* __restrict__ batch,
                                long long n_nodes,
                                const float* __restrict__ pc,
                                float* __restrict__ out) {
    double edge_s = ws[0];
    double prob_s = ws[1];
    double G = (double)(batch[n_nodes - 1] + 1);  // batch is sorted
    double ed = edge_s / G;
    double ew = prob_s / G;
    double loss = (double)pc[0] * ed + ew;
    out[0] = (float)loss;
    out[1] = (float)ew;
    out[2] = (float)ed;
}

extern "C" void kernel_launch(void* const* d_in, const int* in_sizes, int n_in,
                              void* d_out, int out_size, void* d_ws, size_t ws_size,
                              hipStream_t stream) {
    const float* probs = (const float*)d_in[0];
    const int* edge_index = (const int*)d_in[1];   // harness passes integers as int32
    const int* batch = (const int*)d_in[2];
    const float* pc = (const float*)d_in[3];

    long long n_nodes = (long long)in_sizes[0];
    long long n_edges = (long long)in_sizes[1] / 2;
    const int* row = edge_index;
    const int* col = edge_index + n_edges;

    double* ws = (double*)d_ws;
    hipMemsetAsync(ws, 0, 2 * sizeof(double), stream);

    unsigned short* qt = (unsigned short*)((char*)d_ws + 256);
    build_table_kernel<<<512, THREADS, 0, stream>>>(probs, qt, ws, n_nodes);

    long long T = (n_edges >> 2) >> 1;           // 8 edges per thread
    long long blocks = (T + THREADS - 1) / THREADS;
    if (blocks < 1) blocks = 1;
    edge_sum_kernel<<<(int)blocks, THREADS, 0, stream>>>(qt, row, col, ws,
                                                         n_edges, (int)n_nodes);

    finalize_kernel<<<1, 1, 0, stream>>>(ws, batch, n_nodes, pc, (float*)d_out);
}